// Round 1
// baseline (24.114 us; speedup 1.0000x reference)
//
#include <hip/hip_runtime.h>

// ClebschCombiningSingleUnrolledOld: out[b,f,s] = sum_{m1+m2=s, m1,m2<9} X1[b,f,m1]*X2[b,f,m2]*CG[m1,m2]
// B=4096, F=256, L1=L2=9, lambd=4 -> out [B,F,9], all float32.
// Memory-bound: ~113 MB total traffic.

constexpr int L = 9;                     // L1 == L2 == 2*lambd+1
constexpr int ROWS_PER_BLOCK = 256;
constexpr int FLOATS_PER_BLOCK = ROWS_PER_BLOCK * L;   // 2304
constexpr int VEC4_PER_BLOCK   = FLOATS_PER_BLOCK / 4; // 576

__global__ __launch_bounds__(256)
void cg_combine_kernel(const float* __restrict__ X1,
                       const float* __restrict__ X2,
                       const float* __restrict__ CG,
                       float* __restrict__ out,
                       long long total_floats)   // nrows * 9
{
    __shared__ float s1[FLOATS_PER_BLOCK];
    __shared__ float s2[FLOATS_PER_BLOCK];
    __shared__ float so[FLOATS_PER_BLOCK];

    const int tid = threadIdx.x;
    const long long base = (long long)blockIdx.x * FLOATS_PER_BLOCK;
    const long long remaining = total_floats - base;   // >0 by grid construction

    // ---- cooperative global -> LDS staging (float4) ----
    if (remaining >= FLOATS_PER_BLOCK) {
        const float4* X1v = reinterpret_cast<const float4*>(X1 + base);
        const float4* X2v = reinterpret_cast<const float4*>(X2 + base);
        float4* s1v = reinterpret_cast<float4*>(s1);
        float4* s2v = reinterpret_cast<float4*>(s2);
        #pragma unroll
        for (int k = 0; k < 3; ++k) {
            int i = tid + k * 256;
            if (i < VEC4_PER_BLOCK) {
                s1v[i] = X1v[i];
                s2v[i] = X2v[i];
            }
        }
    } else {
        // tail block: scalar guarded loads
        for (int i = tid; i < FLOATS_PER_BLOCK; i += 256) {
            float a = 0.f, b = 0.f;
            if (i < remaining) { a = X1[base + i]; b = X2[base + i]; }
            s1[i] = a; s2[i] = b;
        }
    }
    __syncthreads();

    // ---- per-thread row compute ----
    {
        float x1[L], x2[L];
        #pragma unroll
        for (int j = 0; j < L; ++j) {
            x1[j] = s1[tid * L + j];
            x2[j] = s2[tid * L + j];
        }
        float acc[L];
        #pragma unroll
        for (int s = 0; s < L; ++s) acc[s] = 0.f;

        #pragma unroll
        for (int m1 = 0; m1 < L; ++m1) {
            #pragma unroll
            for (int m2 = 0; m2 + m1 < L; ++m2) {
                // CG address is wave-uniform -> scalar loads, cached
                acc[m1 + m2] = fmaf(x1[m1] * CG[m1 * L + m2], x2[m2], acc[m1 + m2]);
            }
        }
        #pragma unroll
        for (int s = 0; s < L; ++s) so[tid * L + s] = acc[s];
    }
    __syncthreads();

    // ---- cooperative LDS -> global store (float4) ----
    if (remaining >= FLOATS_PER_BLOCK) {
        float4* outv = reinterpret_cast<float4*>(out + base);
        const float4* sov = reinterpret_cast<const float4*>(so);
        #pragma unroll
        for (int k = 0; k < 3; ++k) {
            int i = tid + k * 256;
            if (i < VEC4_PER_BLOCK) outv[i] = sov[i];
        }
    } else {
        for (int i = tid; i < remaining; i += 256) out[base + i] = so[i];
    }
}

extern "C" void kernel_launch(void* const* d_in, const int* in_sizes, int n_in,
                              void* d_out, int out_size, void* d_ws, size_t ws_size,
                              hipStream_t stream) {
    const float* X1 = (const float*)d_in[0];
    const float* X2 = (const float*)d_in[1];
    const float* CG = (const float*)d_in[2];
    float* out = (float*)d_out;

    const long long total_floats = (long long)in_sizes[0];  // B*F*9
    const int nblocks = (int)((total_floats + FLOATS_PER_BLOCK - 1) / FLOATS_PER_BLOCK);

    cg_combine_kernel<<<nblocks, 256, 0, stream>>>(X1, X2, CG, out, total_floats);
}

// Round 2
// 22.708 us; speedup vs baseline: 1.0619x; 1.0619x over previous
//
#include <hip/hip_runtime.h>

// ClebschCombiningSingleUnrolledOld:
//   out[b,f,s] = sum_{m1+m2=s, m1,m2<9} X1[b,f,m1]*X2[b,f,m2]*CG[m1,m2]
// B=4096, F=256, L1=L2=9, lambd=4 -> out [B,F,9], all float32.
// Memory-bound: ~113 MB total traffic. Floor ~18 us @ 6.3 TB/s.
//
// R2 change: reuse s1 as the output staging buffer (each thread reads its own
// row into registers before overwriting the same slots -> no cross-thread
// hazard). LDS 27.6 KB -> 18.4 KB => 8 blocks/CU (full 32 waves/CU) for
// better phase overlap across resident blocks.

constexpr int L = 9;                     // L1 == L2 == 2*lambd+1
constexpr int ROWS_PER_BLOCK = 256;
constexpr int FLOATS_PER_BLOCK = ROWS_PER_BLOCK * L;   // 2304
constexpr int VEC4_PER_BLOCK   = FLOATS_PER_BLOCK / 4; // 576

__global__ __launch_bounds__(256)
void cg_combine_kernel(const float* __restrict__ X1,
                       const float* __restrict__ X2,
                       const float* __restrict__ CG,
                       float* __restrict__ out,
                       long long total_floats)   // nrows * 9
{
    __shared__ float s1[FLOATS_PER_BLOCK];   // input X1 slab, then output slab
    __shared__ float s2[FLOATS_PER_BLOCK];   // input X2 slab

    const int tid = threadIdx.x;
    const long long base = (long long)blockIdx.x * FLOATS_PER_BLOCK;
    const long long remaining = total_floats - base;   // >0 by grid construction
    const bool full = (remaining >= FLOATS_PER_BLOCK);

    // ---- cooperative global -> LDS staging (float4) ----
    if (full) {
        const float4* X1v = reinterpret_cast<const float4*>(X1 + base);
        const float4* X2v = reinterpret_cast<const float4*>(X2 + base);
        float4* s1v = reinterpret_cast<float4*>(s1);
        float4* s2v = reinterpret_cast<float4*>(s2);
        #pragma unroll
        for (int k = 0; k < 3; ++k) {
            int i = tid + k * 256;
            if (i < VEC4_PER_BLOCK) {
                s1v[i] = X1v[i];
                s2v[i] = X2v[i];
            }
        }
    } else {
        for (int i = tid; i < FLOATS_PER_BLOCK; i += 256) {
            float a = 0.f, b = 0.f;
            if (i < remaining) { a = X1[base + i]; b = X2[base + i]; }
            s1[i] = a; s2[i] = b;
        }
    }
    __syncthreads();

    // ---- per-thread row compute; write result back over s1 (own slots) ----
    {
        float x1[L], x2[L];
        #pragma unroll
        for (int j = 0; j < L; ++j) {
            x1[j] = s1[tid * L + j];
            x2[j] = s2[tid * L + j];
        }
        float acc[L];
        #pragma unroll
        for (int s = 0; s < L; ++s) acc[s] = 0.f;

        #pragma unroll
        for (int m1 = 0; m1 < L; ++m1) {
            #pragma unroll
            for (int m2 = 0; m2 + m1 < L; ++m2) {
                // CG address is wave-uniform -> scalar loads, cached
                acc[m1 + m2] = fmaf(x1[m1] * CG[m1 * L + m2], x2[m2], acc[m1 + m2]);
            }
        }
        #pragma unroll
        for (int s = 0; s < L; ++s) s1[tid * L + s] = acc[s];
    }
    __syncthreads();

    // ---- cooperative LDS -> global store (float4) ----
    if (full) {
        float4* outv = reinterpret_cast<float4*>(out + base);
        const float4* sov = reinterpret_cast<const float4*>(s1);
        #pragma unroll
        for (int k = 0; k < 3; ++k) {
            int i = tid + k * 256;
            if (i < VEC4_PER_BLOCK) outv[i] = sov[i];
        }
    } else {
        for (int i = tid; i < remaining; i += 256) out[base + i] = s1[i];
    }
}

extern "C" void kernel_launch(void* const* d_in, const int* in_sizes, int n_in,
                              void* d_out, int out_size, void* d_ws, size_t ws_size,
                              hipStream_t stream) {
    const float* X1 = (const float*)d_in[0];
    const float* X2 = (const float*)d_in[1];
    const float* CG = (const float*)d_in[2];
    float* out = (float*)d_out;

    const long long total_floats = (long long)in_sizes[0];  // B*F*9
    const int nblocks = (int)((total_floats + FLOATS_PER_BLOCK - 1) / FLOATS_PER_BLOCK);

    cg_combine_kernel<<<nblocks, 256, 0, stream>>>(X1, X2, CG, out, total_floats);
}

// Round 4
// 22.173 us; speedup vs baseline: 1.0875x; 1.0242x over previous
//
#include <hip/hip_runtime.h>

// ClebschCombiningSingleUnrolledOld:
//   out[b,f,s] = sum_{m1+m2=s, m1,m2<9} X1[b,f,m1]*X2[b,f,m2]*CG[m1,m2]
// B=4096, F=256, L1=L2=9, lambd=4 -> out [B,F,9], all float32.
// Memory-bound: ~113 MB total traffic. Floor ~18 us @ 6.3 TB/s copy ceiling.
//
// R4 = R3 with the compile fix: nontemporal store uses a native clang vector
// (ext_vector_type(4)), not HIP's float4 class.
//  - global->LDS staging via __builtin_amdgcn_global_load_lds (width=16)
//  - nontemporal float4 output stores
//  - output staged back through s1: LDS 18.4 KB -> 8 blocks/CU (32 waves/CU)

constexpr int L = 9;                     // L1 == L2 == 2*lambd+1
constexpr int ROWS_PER_BLOCK = 256;
constexpr int FLOATS_PER_BLOCK = ROWS_PER_BLOCK * L;   // 2304
constexpr int VEC4_PER_BLOCK   = FLOATS_PER_BLOCK / 4; // 576

typedef float __attribute__((ext_vector_type(4))) floatx4;   // native vector

typedef __attribute__((address_space(3))) unsigned int       lds_u32;
typedef const __attribute__((address_space(1))) unsigned int glb_u32;

__device__ __forceinline__ void gload_lds16(const float* gsrc, float* ldsdst) {
    // 16-byte direct global->LDS DMA; LDS dest = wave-uniform base + lane*16.
    __builtin_amdgcn_global_load_lds((glb_u32*)gsrc, (lds_u32*)ldsdst, 16, 0, 0);
}

__global__ __launch_bounds__(256)
void cg_combine_kernel(const float* __restrict__ X1,
                       const float* __restrict__ X2,
                       const float* __restrict__ CG,
                       float* __restrict__ out,
                       long long total_floats)   // nrows * 9
{
    __shared__ float s1[FLOATS_PER_BLOCK];   // X1 slab in, output slab out
    __shared__ float s2[FLOATS_PER_BLOCK];   // X2 slab

    const int tid = threadIdx.x;
    const long long base = (long long)blockIdx.x * FLOATS_PER_BLOCK;
    const long long remaining = total_floats - base;   // >0 by grid construction
    const bool full = (remaining >= FLOATS_PER_BLOCK);

    // ---- staging: direct global -> LDS DMA (float4 granularity) ----
    if (full) {
        #pragma unroll
        for (int k = 0; k < 3; ++k) {
            const int i = tid + k * 256;           // float4 index in slab
            if (i < VEC4_PER_BLOCK) {              // whole waves active/inactive
                gload_lds16(X1 + base + (long long)i * 4, s1 + i * 4);
                gload_lds16(X2 + base + (long long)i * 4, s2 + i * 4);
            }
        }
    } else {
        for (int i = tid; i < FLOATS_PER_BLOCK; i += 256) {
            float a = 0.f, b = 0.f;
            if (i < remaining) { a = X1[base + i]; b = X2[base + i]; }
            s1[i] = a; s2[i] = b;
        }
    }
    __syncthreads();   // compiler emits vmcnt(0)+lgkmcnt(0) drain before barrier

    // ---- per-thread row compute; write result back over s1 (own slots) ----
    {
        float x1[L], x2[L];
        #pragma unroll
        for (int j = 0; j < L; ++j) {
            x1[j] = s1[tid * L + j];
            x2[j] = s2[tid * L + j];
        }
        float acc[L];
        #pragma unroll
        for (int s = 0; s < L; ++s) acc[s] = 0.f;

        #pragma unroll
        for (int m1 = 0; m1 < L; ++m1) {
            #pragma unroll
            for (int m2 = 0; m2 + m1 < L; ++m2) {
                // CG address is wave-uniform -> scalar s_load, cached
                acc[m1 + m2] = fmaf(x1[m1] * CG[m1 * L + m2], x2[m2], acc[m1 + m2]);
            }
        }
        #pragma unroll
        for (int s = 0; s < L; ++s) s1[tid * L + s] = acc[s];
    }
    __syncthreads();

    // ---- cooperative LDS -> global store (nontemporal float4) ----
    if (full) {
        floatx4* outv = reinterpret_cast<floatx4*>(out + base);
        const floatx4* sov = reinterpret_cast<const floatx4*>(s1);
        #pragma unroll
        for (int k = 0; k < 3; ++k) {
            const int i = tid + k * 256;
            if (i < VEC4_PER_BLOCK) {
                __builtin_nontemporal_store(sov[i], &outv[i]);
            }
        }
    } else {
        for (int i = tid; i < remaining; i += 256) out[base + i] = s1[i];
    }
}

extern "C" void kernel_launch(void* const* d_in, const int* in_sizes, int n_in,
                              void* d_out, int out_size, void* d_ws, size_t ws_size,
                              hipStream_t stream) {
    const float* X1 = (const float*)d_in[0];
    const float* X2 = (const float*)d_in[1];
    const float* CG = (const float*)d_in[2];
    float* out = (float*)d_out;

    const long long total_floats = (long long)in_sizes[0];  // B*F*9
    const int nblocks = (int)((total_floats + FLOATS_PER_BLOCK - 1) / FLOATS_PER_BLOCK);

    cg_combine_kernel<<<nblocks, 256, 0, stream>>>(X1, X2, CG, out, total_floats);
}